// Round 1
// baseline (566.378 us; speedup 1.0000x reference)
//
#include <hip/hip_runtime.h>
#include <math.h>

#define BB 32
#define CC 256
#define CQ 32      // C/8
#define NN 1024    // H*W

// ---------------------------------------------------------------------------
// Kernel 1: fused QKV projection.
// grid (16 n-tiles, 32 batches), block 256 (4 waves).
// Stores q [B][32][N], k [B][32][N], v [B][256][N]  (N contiguous, coalesced).
// ---------------------------------------------------------------------------
__device__ __forceinline__ void proj8(const float xs[CC][64],
                                      const float* __restrict__ W,
                                      const float* __restrict__ bias,
                                      int r0, int n,
                                      float* __restrict__ outbase /* + b*R*N + n0 + n */)
{
    float acc[8];
#pragma unroll
    for (int i = 0; i < 8; ++i) acc[i] = bias[r0 + i];
#pragma unroll 4
    for (int c = 0; c < CC; ++c) {
        const float xv = xs[c][n];
#pragma unroll
        for (int i = 0; i < 8; ++i)
            acc[i] = fmaf(W[(size_t)(r0 + i) * CC + c], xv, acc[i]);
    }
#pragma unroll
    for (int i = 0; i < 8; ++i)
        outbase[(size_t)(r0 + i) * NN] = acc[i];
}

__global__ __launch_bounds__(256, 2) void qkv_proj_kernel(
    const float* __restrict__ x,
    const float* __restrict__ Wq, const float* __restrict__ bq,
    const float* __restrict__ Wk, const float* __restrict__ bk,
    const float* __restrict__ Wv, const float* __restrict__ bv,
    float* __restrict__ qo, float* __restrict__ ko, float* __restrict__ vo)
{
    __shared__ float xs[CC][64];                 // 64 KB
    const int b  = blockIdx.y;
    const int n0 = blockIdx.x * 64;
    const int t  = threadIdx.x;

    // stage x tile [256 c][64 n], fully coalesced float4
    {
        const int cr = t >> 4;                   // 0..15
        const int jj = t & 15;                   // float4 col
        const float* xb = x + (size_t)b * CC * NN + n0;
#pragma unroll
        for (int s = 0; s < 16; ++s) {
            const float4 val = *(const float4*)(xb + (size_t)(cr + 16 * s) * NN + jj * 4);
            *(float4*)&xs[cr + 16 * s][jj * 4] = val;
        }
    }
    __syncthreads();

    const int n = t & 63;
    // wave id — force SGPR so W reads become s_load (wave-uniform)
    const int g = __builtin_amdgcn_readfirstlane(t >> 6);   // 0..3

    // Q rows g*8..g*8+7
    proj8(xs, Wq, bq, g * 8, n, qo + (size_t)b * CQ * NN + n0 + n);
    // K rows
    proj8(xs, Wk, bk, g * 8, n, ko + (size_t)b * CQ * NN + n0 + n);
    // V rows: 64 rows per wave-group, 8 chunks of 8
    for (int ch = 0; ch < 8; ++ch)
        proj8(xs, Wv, bv, g * 64 + ch * 8, n, vo + (size_t)b * CC * NN + n0 + n);
}

// ---------------------------------------------------------------------------
// Kernel 2: flash-style fused attention + residual.
// grid (16 m-tiles, 32 batches), block 256 (4 waves), 2 blocks/CU.
// Thread t: energy phase  (nt = t&31 key-lane, mg = t>>5 owns 8 m-rows)
//           PV phase      (tc = t&31 chan-lane, same mg) -> M/l/alpha stay in regs.
// ---------------------------------------------------------------------------
__global__ __launch_bounds__(256, 2) void attn_kernel(
    const float* __restrict__ qo, const float* __restrict__ ko,
    const float* __restrict__ vo, const float* __restrict__ x,
    const float* __restrict__ gamma_p,
    float* __restrict__ out)
{
    __shared__ float qs[CQ][64];     // [d][m]   8 KB
    __shared__ float ks[CQ][32];     // [d][n]   4 KB
    __shared__ float vs[CC][33];     // [c][n]  pad +1 -> conflict-free strided reads
    __shared__ float ps[64][32];     // [m][n]   8 KB

    const int b  = blockIdx.y;
    const int m0 = blockIdx.x * 64;
    const int t  = threadIdx.x;

    // load q tile [32 d][64 m]
    {
        const int d  = t >> 4;                    // 0..15 (+16)
        const int jj = t & 15;
        const float* qb = qo + (size_t)b * CQ * NN + m0;
#pragma unroll
        for (int s = 0; s < 2; ++s) {
            const float4 val = *(const float4*)(qb + (size_t)(d + 16 * s) * NN + jj * 4);
            *(float4*)&qs[d + 16 * s][jj * 4] = val;
        }
    }

    const int nt = t & 31;        // energy: key lane
    const int mg = t >> 5;        // m-group 0..7 (same group in both phases)
    const int tc = t & 31;        // PV: channel lane

    float M[8], l[8], alpha[8];
    float acc[8][8];
#pragma unroll
    for (int i = 0; i < 8; ++i) { M[i] = -INFINITY; l[i] = 0.f; }
#pragma unroll
    for (int i = 0; i < 8; ++i)
#pragma unroll
        for (int j = 0; j < 8; ++j) acc[i][j] = 0.f;

    const int kr = t >> 3;        // 0..31 staging row
    const int kj = t & 7;         // float4 idx
    const float* kb = ko + (size_t)b * CQ * NN;
    const float* vb = vo + (size_t)b * CC * NN;

    for (int tile = 0; tile < NN / 32; ++tile) {
        const int n0t = tile * 32;

        // prefetch next tiles into registers (overlaps with prev phase B)
        const float4 kf = *(const float4*)(kb + (size_t)kr * NN + n0t + kj * 4);
        float4 vf[8];
#pragma unroll
        for (int s = 0; s < 8; ++s)
            vf[s] = *(const float4*)(vb + (size_t)(kr + 32 * s) * NN + n0t + kj * 4);

        __syncthreads();          // prev phase B done with vs/ps (also: qs staged, 1st iter)

        *(float4*)&ks[kr][kj * 4] = kf;
#pragma unroll
        for (int s = 0; s < 8; ++s) {
            float* vrow = &vs[kr + 32 * s][kj * 4];
            vrow[0] = vf[s].x; vrow[1] = vf[s].y; vrow[2] = vf[s].z; vrow[3] = vf[s].w;
        }
        __syncthreads();          // ks/vs staged

        // ---- energy: e[m][nt] = q[m] . k[nt], 8 m-rows per thread ----
        float e[8];
#pragma unroll
        for (int i = 0; i < 8; ++i) e[i] = 0.f;
#pragma unroll 4
        for (int d = 0; d < CQ; ++d) {
            const float kd = ks[d][nt];
#pragma unroll
            for (int i = 0; i < 8; ++i)
                e[i] = fmaf(qs[d][mg * 8 + i], kd, e[i]);
        }

        // ---- online softmax over the 32 key-lanes of this group ----
#pragma unroll
        for (int i = 0; i < 8; ++i) {
            float em = e[i];
#pragma unroll
            for (int msk = 16; msk >= 1; msk >>= 1)
                em = fmaxf(em, __shfl_xor(em, msk));
            const float Mn = fmaxf(M[i], em);
            const float a  = __expf(M[i] - Mn);       // first tile: exp(-inf)=0
            const float p  = __expf(e[i] - Mn);
            float rs = p;
#pragma unroll
            for (int msk = 16; msk >= 1; msk >>= 1)
                rs += __shfl_xor(rs, msk);
            l[i]     = l[i] * a + rs;
            M[i]     = Mn;
            alpha[i] = a;
            ps[mg * 8 + i][nt] = p;
        }
        __syncthreads();          // ps ready

        // ---- PV accumulate: acc[m][c] += p[m][n] * v[c][n] ----
#pragma unroll
        for (int i = 0; i < 8; ++i)
#pragma unroll
            for (int j = 0; j < 8; ++j) acc[i][j] *= alpha[i];

        for (int nn = 0; nn < 32; ++nn) {
            float vvv[8], pp[8];
#pragma unroll
            for (int j = 0; j < 8; ++j) vvv[j] = vs[tc + 32 * j][nn];  // bank (tc+nn)%32: conflict-free
#pragma unroll
            for (int i = 0; i < 8; ++i) pp[i] = ps[mg * 8 + i][nn];    // broadcast
#pragma unroll
            for (int i = 0; i < 8; ++i)
#pragma unroll
                for (int j = 0; j < 8; ++j)
                    acc[i][j] = fmaf(pp[i], vvv[j], acc[i][j]);
        }
    }

    // ---- epilogue: out = gamma * (acc/l) + x ----
    const float gamma = gamma_p[0];
    float inv[8];
#pragma unroll
    for (int i = 0; i < 8; ++i) inv[i] = 1.0f / l[i];

#pragma unroll
    for (int j = 0; j < 8; ++j) {
        const int c = tc + 32 * j;
        const float* xrow = x   + (size_t)b * CC * NN + (size_t)c * NN + m0 + mg * 8;
        float*       orow = out + (size_t)b * CC * NN + (size_t)c * NN + m0 + mg * 8;
        const float4 x0 = *(const float4*)(xrow);
        const float4 x1 = *(const float4*)(xrow + 4);
        float4 o0, o1;
        o0.x = gamma * acc[0][j] * inv[0] + x0.x;
        o0.y = gamma * acc[1][j] * inv[1] + x0.y;
        o0.z = gamma * acc[2][j] * inv[2] + x0.z;
        o0.w = gamma * acc[3][j] * inv[3] + x0.w;
        o1.x = gamma * acc[4][j] * inv[4] + x1.x;
        o1.y = gamma * acc[5][j] * inv[5] + x1.y;
        o1.z = gamma * acc[6][j] * inv[6] + x1.z;
        o1.w = gamma * acc[7][j] * inv[7] + x1.w;
        *(float4*)(orow)     = o0;
        *(float4*)(orow + 4) = o1;
    }
}

// ---------------------------------------------------------------------------
extern "C" void kernel_launch(void* const* d_in, const int* in_sizes, int n_in,
                              void* d_out, int out_size, void* d_ws, size_t ws_size,
                              hipStream_t stream)
{
    const float* x  = (const float*)d_in[0];
    const float* Wq = (const float*)d_in[1];
    const float* bq = (const float*)d_in[2];
    const float* Wk = (const float*)d_in[3];
    const float* bk = (const float*)d_in[4];
    const float* Wv = (const float*)d_in[5];
    const float* bv = (const float*)d_in[6];
    const float* gm = (const float*)d_in[7];
    float* out = (float*)d_out;

    // workspace: q 4MB, k 4MB, v 32MB  (total 40 MB)
    float* qw = (float*)d_ws;
    float* kw = qw + (size_t)BB * CQ * NN;
    float* vw = kw + (size_t)BB * CQ * NN;

    dim3 grid(16, BB);
    qkv_proj_kernel<<<grid, 256, 0, stream>>>(x, Wq, bq, Wk, bk, Wv, bv, qw, kw, vw);
    attn_kernel<<<grid, 256, 0, stream>>>(qw, kw, vw, x, gm, out);
}

// Round 2
// 208.185 us; speedup vs baseline: 2.7205x; 2.7205x over previous
//
#include <hip/hip_runtime.h>
#include <math.h>

#define BB 32
#define CC 256
#define CQ 32      // C/8
#define NN 1024    // H*W

typedef short bf16x8 __attribute__((ext_vector_type(8)));
typedef float f32x4  __attribute__((ext_vector_type(4)));
typedef unsigned short u16;

// fp32 -> bf16 RNE
__device__ __forceinline__ u16 f2bf(float f) {
    unsigned u = __float_as_uint(f);
    u = (u + 0x7FFFu + ((u >> 16) & 1u)) >> 16;
    return (u16)u;
}

// ---------------------------------------------------------------------------
// Kernel 0: pack fused W = [Wq(32); Wk(32); Wv(256)] rows x 256 cols to bf16.
// ---------------------------------------------------------------------------
__global__ void wpack_kernel(const float* __restrict__ Wq,
                             const float* __restrict__ Wk,
                             const float* __restrict__ Wv,
                             u16* __restrict__ wbf)
{
    const int idx = blockIdx.x * 256 + threadIdx.x;   // 0 .. 81919
    const int r = idx >> 8, c = idx & 255;
    const float v = (r < 32) ? Wq[r * 256 + c]
                  : (r < 64) ? Wk[(r - 32) * 256 + c]
                             : Wv[(r - 64) * 256 + c];
    wbf[idx] = f2bf(v);
}

// ---------------------------------------------------------------------------
// Kernel 1: QKV projection via MFMA. grid(16 n-tiles, 32 b), 256 thr.
// Outputs: qt,kt as [b][n][32 d] bf16 (d contig) ; vv as [b][c][n] bf16.
// ---------------------------------------------------------------------------
__global__ __launch_bounds__(256, 2) void qkv_kernel(
    const float* __restrict__ x, const u16* __restrict__ wbf,
    const float* __restrict__ bq, const float* __restrict__ bk,
    const float* __restrict__ bv,
    u16* __restrict__ qt, u16* __restrict__ kt, u16* __restrict__ vv)
{
    __shared__ u16 xs[64][264];                  // x^T tile [n][c] bf16, 33.8 KB
    const int b = blockIdx.y, n0 = blockIdx.x * 64;
    const int t = threadIdx.x;
    const int lane = t & 63, w = t >> 6;
    const int quad = lane >> 4, c16 = lane & 15;

    // stage x^T (coalesced float4 reads, scattered bf16 writes — one-time)
    {
        const int cr = t >> 4, jj = t & 15;
        const float* xb = x + (size_t)b * CC * NN + n0;
#pragma unroll
        for (int it = 0; it < 16; ++it) {
            const int c = cr + 16 * it;
            const float4 f = *(const float4*)(xb + (size_t)c * NN + jj * 4);
            xs[4 * jj + 0][c] = f2bf(f.x);
            xs[4 * jj + 1][c] = f2bf(f.y);
            xs[4 * jj + 2][c] = f2bf(f.z);
            xs[4 * jj + 3][c] = f2bf(f.w);
        }
    }
    __syncthreads();

    f32x4 acc[5][4];
#pragma unroll
    for (int i = 0; i < 5; ++i)
#pragma unroll
        for (int j = 0; j < 4; ++j) acc[i][j] = (f32x4){0.f, 0.f, 0.f, 0.f};

#pragma unroll
    for (int k = 0; k < 8; ++k) {
        const int c0 = k * 32;
        bf16x8 wa[5], xb[4];
#pragma unroll
        for (int rs = 0; rs < 5; ++rs) {
            const int rg = w * 80 + rs * 16 + c16;        // A: m = lane&15
            wa[rs] = *(const bf16x8*)&wbf[(size_t)rg * 256 + c0 + quad * 8];
        }
#pragma unroll
        for (int ns = 0; ns < 4; ++ns)                    // B: n-col = lane&15
            xb[ns] = *(const bf16x8*)&xs[ns * 16 + c16][c0 + quad * 8];
#pragma unroll
        for (int rs = 0; rs < 5; ++rs)
#pragma unroll
            for (int ns = 0; ns < 4; ++ns)
                acc[rs][ns] = __builtin_amdgcn_mfma_f32_16x16x32_bf16(
                    wa[rs], xb[ns], acc[rs][ns], 0, 0, 0);
    }

    // epilogue: D row = quad*4+reg, col = lane&15
#pragma unroll
    for (int rs = 0; rs < 5; ++rs) {
        const int rbase = w * 80 + rs * 16 + quad * 4;
#pragma unroll
        for (int r = 0; r < 4; ++r) {
            const int rg = rbase + r;
            const float bias = (rg < 32) ? bq[rg] : (rg < 64) ? bk[rg - 32] : bv[rg - 64];
#pragma unroll
            for (int ns = 0; ns < 4; ++ns) {
                const int n = n0 + ns * 16 + c16;
                const u16 h = f2bf(acc[rs][ns][r] + bias);
                if (rg < 32)
                    qt[((size_t)b * NN + n) * CQ + rg] = h;
                else if (rg < 64)
                    kt[((size_t)b * NN + n) * CQ + (rg - 32)] = h;
                else
                    vv[(size_t)b * CC * NN + (size_t)(rg - 64) * NN + n] = h;
            }
        }
    }
}

// ---------------------------------------------------------------------------
// Kernel 2: flash attention via MFMA, O^T formulation. grid(16 m-tiles, 32 b).
// Wave w: S/softmax for m-sub w (16 rows); PV for c-strip w*64 (64 chans).
// ---------------------------------------------------------------------------
__global__ __launch_bounds__(256, 2) void attn_kernel(
    const u16* __restrict__ qt, const u16* __restrict__ kt,
    const u16* __restrict__ vv, const float* __restrict__ x,
    const float* __restrict__ gamma_p, float* __restrict__ out)
{
    __shared__ u16   vs[CC][72];     // V tile [c][n-step] bf16, 36.9 KB
    __shared__ float ps[64][68];     // P tile [m][n-step] f32, 17.4 KB
    __shared__ float als[64];        // alpha per m (this step)
    __shared__ float ls[64];         // final l per m

    const int b = blockIdx.y, m0 = blockIdx.x * 64;
    const int t = threadIdx.x, lane = t & 63, w = t >> 6;
    const int quad = lane >> 4, c16 = lane & 15;

    // Q A-frag: Q[m=lane&15][d=quad*8+j], coalesced 16B from qt[b][m][d]
    const bf16x8 qa = *(const bf16x8*)&qt[((size_t)b * NN + m0 + w * 16 + c16) * CQ + quad * 8];

    f32x4 accO[4][4];                // [cs][ms] of O^T: row=c, col=m
#pragma unroll
    for (int i = 0; i < 4; ++i)
#pragma unroll
        for (int j = 0; j < 4; ++j) accO[i][j] = (f32x4){0.f, 0.f, 0.f, 0.f};
    float M[4], l[4];
#pragma unroll
    for (int r = 0; r < 4; ++r) { M[r] = -INFINITY; l[r] = 0.f; }

    const int cstage = t >> 2;       // 0..63 (+64*cc): V staging row
    const int nch    = t & 3;        // 16-elem n-chunk

    for (int step = 0; step < 16; ++step) {
        const int nbase = step * 64;

        // global loads first (latency overlap with barrier)
        uint4 vreg[4][2];
#pragma unroll
        for (int cc = 0; cc < 4; ++cc) {
            const u16* src = &vv[(size_t)b * CC * NN + (size_t)(cstage + 64 * cc) * NN + nbase + nch * 16];
            vreg[cc][0] = *(const uint4*)(src);
            vreg[cc][1] = *(const uint4*)(src + 8);
        }
        bf16x8 kb[4];
#pragma unroll
        for (int s = 0; s < 4; ++s)   // B: n-col = lane&15, k=d=quad*8+j
            kb[s] = *(const bf16x8*)&kt[((size_t)b * NN + nbase + s * 16 + c16) * CQ + quad * 8];

        __syncthreads();             // previous PV done with vs/ps/als

#pragma unroll
        for (int cc = 0; cc < 4; ++cc) {
            *(uint4*)&vs[cstage + 64 * cc][nch * 16]     = vreg[cc][0];
            *(uint4*)&vs[cstage + 64 * cc][nch * 16 + 8] = vreg[cc][1];
        }

        // ---- S = Q·K^T strip [16 m][64 n] ----
        f32x4 accS[4];
#pragma unroll
        for (int s = 0; s < 4; ++s)
            accS[s] = __builtin_amdgcn_mfma_f32_16x16x32_bf16(
                qa, kb[s], (f32x4){0.f, 0.f, 0.f, 0.f}, 0, 0, 0);

        // ---- online softmax, rows r = quad*4+reg, cols = s*16 + lane&15 ----
        float alpha[4];
#pragma unroll
        for (int r = 0; r < 4; ++r) {
            float em = fmaxf(fmaxf(accS[0][r], accS[1][r]), fmaxf(accS[2][r], accS[3][r]));
#pragma unroll
            for (int msk = 8; msk >= 1; msk >>= 1)
                em = fmaxf(em, __shfl_xor(em, msk));
            const float Mn = fmaxf(M[r], em);
            const float a  = __expf(M[r] - Mn);      // first step: exp(-inf)=0
            float sum = 0.f;
#pragma unroll
            for (int s = 0; s < 4; ++s) {
                const float p = __expf(accS[s][r] - Mn);
                ps[w * 16 + quad * 4 + r][s * 16 + c16] = p;
                sum += p;
            }
#pragma unroll
            for (int msk = 8; msk >= 1; msk >>= 1)
                sum += __shfl_xor(sum, msk);
            l[r] = l[r] * a + sum;
            M[r] = Mn;
            alpha[r] = a;
        }
        if (c16 == 0) {
#pragma unroll
            for (int r = 0; r < 4; ++r) als[w * 16 + quad * 4 + r] = alpha[r];
        }

        __syncthreads();             // vs, ps, als ready

        // ---- PV: O^T[c][m] += V^T[c][n] · P^T[n][m] ----
        bf16x8 va[4][2];
#pragma unroll
        for (int cs = 0; cs < 4; ++cs)
#pragma unroll
            for (int kc = 0; kc < 2; ++kc)   // A: c-row = lane&15, k=n=quad*8+j
                va[cs][kc] = *(const bf16x8*)&vs[w * 64 + cs * 16 + c16][kc * 32 + quad * 8];
        float aw[4];
#pragma unroll
        for (int ms = 0; ms < 4; ++ms) aw[ms] = als[ms * 16 + c16];

#pragma unroll
        for (int ms = 0; ms < 4; ++ms) {
            bf16x8 pb[2];
#pragma unroll
            for (int kc = 0; kc < 2; ++kc) { // B: k=n=quad*8+j, m-col = lane&15
                const f32x4 p0 = *(const f32x4*)&ps[ms * 16 + c16][kc * 32 + quad * 8];
                const f32x4 p1 = *(const f32x4*)&ps[ms * 16 + c16][kc * 32 + quad * 8 + 4];
                bf16x8 pk;
                pk[0] = (short)f2bf(p0[0]); pk[1] = (short)f2bf(p0[1]);
                pk[2] = (short)f2bf(p0[2]); pk[3] = (short)f2bf(p0[3]);
                pk[4] = (short)f2bf(p1[0]); pk[5] = (short)f2bf(p1[1]);
                pk[6] = (short)f2bf(p1[2]); pk[7] = (short)f2bf(p1[3]);
                pb[kc] = pk;
            }
#pragma unroll
            for (int cs = 0; cs < 4; ++cs) {
                accO[cs][ms] *= aw[ms];
#pragma unroll
                for (int kc = 0; kc < 2; ++kc)
                    accO[cs][ms] = __builtin_amdgcn_mfma_f32_16x16x32_bf16(
                        va[cs][kc], pb[kc], accO[cs][ms], 0, 0, 0);
            }
        }
    }

    // ---- epilogue: out = gamma * O / l + x ----
    if (c16 == 0) {
#pragma unroll
        for (int r = 0; r < 4; ++r) ls[w * 16 + quad * 4 + r] = l[r];
    }
    __syncthreads();
    const float gamma = gamma_p[0];
#pragma unroll
    for (int ms = 0; ms < 4; ++ms) {
        const float linv = 1.0f / ls[ms * 16 + c16];
        const int m = m0 + ms * 16 + c16;
#pragma unroll
        for (int cs = 0; cs < 4; ++cs) {
            const int cbase = w * 64 + cs * 16 + quad * 4;
#pragma unroll
            for (int r = 0; r < 4; ++r) {
                const size_t idx = ((size_t)b * CC + cbase + r) * NN + m;
                out[idx] = gamma * accO[cs][ms][r] * linv + x[idx];
            }
        }
    }
}

// ---------------------------------------------------------------------------
extern "C" void kernel_launch(void* const* d_in, const int* in_sizes, int n_in,
                              void* d_out, int out_size, void* d_ws, size_t ws_size,
                              hipStream_t stream)
{
    const float* x  = (const float*)d_in[0];
    const float* Wq = (const float*)d_in[1];
    const float* bq = (const float*)d_in[2];
    const float* Wk = (const float*)d_in[3];
    const float* bk = (const float*)d_in[4];
    const float* Wv = (const float*)d_in[5];
    const float* bv = (const float*)d_in[6];
    const float* gm = (const float*)d_in[7];
    float* out = (float*)d_out;

    // workspace (bf16): qt 2MB | kt 2MB | vv 16MB | wbf 160KB
    u16* qt  = (u16*)d_ws;
    u16* kt  = qt + (size_t)BB * NN * CQ;
    u16* vv  = kt + (size_t)BB * NN * CQ;
    u16* wbf = vv + (size_t)BB * CC * NN;

    wpack_kernel<<<320, 256, 0, stream>>>(Wq, Wk, Wv, wbf);
    dim3 grid(16, BB);
    qkv_kernel<<<grid, 256, 0, stream>>>(x, wbf, bq, bk, bv, qt, kt, vv);
    attn_kernel<<<grid, 256, 0, stream>>>(qt, kt, vv, x, gm, out);
}